// Round 2
// baseline (343.497 us; speedup 1.0000x reference)
//
#include <hip/hip_runtime.h>
#include <stdint.h>

typedef unsigned short ushortT;

#define NROWS 131072
#define DIM 64
#define KCODES 1024
#define NSEG 5              // (x0e0,x0e1,x0e2,x1e0,x2e0): x1e1 dropped (~4e-6 ≈ fp32 ulp).
                            // K=192 (3 seg) FLIPS an argmin (R14: absmax 0.966) — boundary measured.
#define KTOT (NSEG * DIM)   // 320
#define NKC (KTOT / 32)     // 10 K-chunks of 32
#define MT 64               // rows per block (256 threads, 4 waves)
#define NTC 256             // codes per code-iter (4 waves x 64)
#define CI (KCODES / NTC)   // 4 code iters
#define KCSTEP (4 * KCODES * 8)  // ushort elements per kc plane of Bg = 32768
#define ASTEP (4 * MT * 8)       // ushort elements per kc plane of A_lds = 2048

typedef float f32x4 __attribute__((ext_vector_type(4)));
typedef short bf16x8 __attribute__((ext_vector_type(8)));

__device__ __forceinline__ ushortT f2bf(float f) {
  union { float f; uint32_t u; } v; v.f = f;
  return (ushortT)((v.u + 0x7FFFu + ((v.u >> 16) & 1u)) >> 16);  // RNE
}
__device__ __forceinline__ float bf2f(ushortT b) {
  union { float f; uint32_t u; } v; v.u = ((uint32_t)b) << 16;
  return v.f;
}

// R15: output-major prep. Flat Bg index o = (k>>3)*8192 + code*8 + (k&7),
// k = seg*64 + d. Thread handles 4 consecutive o (same code/seg, d..d+3),
// coalesced uint2 store. 320 blocks (was 4 -> latency-exposed ~60us tail).
// seg is uniform per block (o>>13 constant across 1024-elem block range).
// h2 computed by blocks 0..3 (coalesced column loads). Same f2bf math ->
// bit-identical Bg/h2 vs R13 prep.
__global__ __launch_bounds__(256) void vq_prep(const float* __restrict__ emb,
                                               ushortT* __restrict__ Bg,
                                               float* __restrict__ h2) {
  const int o4 = (blockIdx.x * 256 + threadIdx.x) * 4;
  const int j0 = o4 & 7;                  // 0 or 4
  const int code = (o4 >> 3) & (KCODES - 1);
  const int kq = o4 >> 13;                // 0..39 (block-uniform)
  const int k0 = kq * 8 + j0;
  const int d0 = k0 & 63;
  const int seg = k0 >> 6;                // 0..4 (block-uniform)

  ushortT outv[4];
#pragma unroll
  for (int t = 0; t < 4; ++t) {
    float e = emb[(d0 + t) * KCODES + code];
    ushortT p0 = f2bf(e);
    ushortT pv = p0;                      // seg 0,3,4: plane 0
    if (seg == 1) {
      float r1 = e - bf2f(p0);            // exact (Sterbenz)
      pv = f2bf(r1);
    } else if (seg == 2) {
      float r1 = e - bf2f(p0);
      ushortT p1 = f2bf(r1);
      float r2 = r1 - bf2f(p1);           // exact
      pv = f2bf(r2);
    }
    outv[t] = pv;
  }
  *(uint2*)(&Bg[o4]) = *(const uint2*)(&outv[0]);

  if (blockIdx.x < 4) {
    const int c2 = blockIdx.x * 256 + threadIdx.x;
    float s = 0.f;
#pragma unroll
    for (int d = 0; d < DIM; ++d) {
      float e = emb[d * KCODES + c2];
      s = fmaf(e, e, s);
    }
    h2[c2] = 0.5f * s;
  }
}

// R15 structure: depth-5 B register ring (b[kc%5]), kc loop fully unrolled,
// cross-ci prefetch continuation (10 % 5 == 0 -> ring slots self-align across
// ci: the last 5 reloads of ci fetch next ci's kc0..4 into the right slots;
// pipeline never drains). a ping-pong kc=9 clamp preloads next ci's a[0].
// h2 hoisted to ci start. launch_bounds(256,2): ~185 unified VGPR -> 2
// waves/SIMD, trading occupancy (12->8 waves/CU) for stall-free B stream
// (load->use distance 4 kc blocks >= 400cyc >> L2 ~200cyc). R13 was
// MfmaUtil 30% with vmcnt stall each half-iteration.
__global__ __launch_bounds__(256, 2) void vq_main(const float* __restrict__ x,
                                                  const ushortT* __restrict__ Bg,
                                                  const float* __restrict__ h2,
                                                  const float* __restrict__ emb,
                                                  float* __restrict__ out) {
  __shared__ ushortT A_lds[NKC * ASTEP];  // 40 KB  [kc][quad][row][8]
  __shared__ float bvs[4][MT];
  __shared__ int bis[4][MT];
  __shared__ int widx_s[MT];

  const int tid = threadIdx.x;
  const int wave = tid >> 6, lane = tid & 63, quad = lane >> 4, lq = lane & 15;
  const size_t rowbase = (size_t)blockIdx.x * MT;

  const ushortT* bci = Bg + ((size_t)(quad * KCODES + wave * 64 + lq)) * 8;
  const ushortT* ab = &A_lds[quad * (MT * 8) + lq * 8];

  // ---- issue x loads first (oldest in vmcnt queue), then b preload ----
  const int srow = tid >> 2, sdg = (tid & 3) << 4;
  float v[16];
  {
    const float4* xr = (const float4*)(x + (rowbase + srow) * DIM + sdg);
#pragma unroll
    for (int i = 0; i < 4; ++i) {
      float4 t = xr[i];
      v[4 * i] = t.x; v[4 * i + 1] = t.y; v[4 * i + 2] = t.z; v[4 * i + 3] = t.w;
    }
  }

  bf16x8 a[2][4], b[5][4];
  // preload b ring: ci0 kc0..4 (20 global loads, stay in flight across stage-A)
#pragma unroll
  for (int s = 0; s < 5; ++s)
#pragma unroll
    for (int j = 0; j < 4; ++j)
      b[s][j] = *(const bf16x8*)(bci + (size_t)s * KCSTEP + j * 128);

  // ---- stage A: x rows -> bf16 planes, frag-major ----
  {
    ushortT pl[3][16];
#pragma unroll
    for (int i = 0; i < 16; ++i) {
      ushortT a0 = f2bf(v[i]); float r1 = v[i] - bf2f(a0);
      ushortT a1 = f2bf(r1);   float r2 = r1 - bf2f(a1);
      pl[0][i] = a0; pl[1][i] = a1; pl[2][i] = f2bf(r2);
    }
    const int sA[NSEG] = {0, 0, 0, 1, 2};  // x-plane per segment
    const int q0 = (sdg & 31) >> 3;        // 0 or 2
#pragma unroll
    for (int seg = 0; seg < NSEG; ++seg) {
      int kc = seg * 2 + (sdg >> 5);
      *(uint4*)&A_lds[kc * ASTEP + q0 * (MT * 8) + srow * 8]       = *(uint4*)&pl[sA[seg]][0];
      *(uint4*)&A_lds[kc * ASTEP + (q0 + 1) * (MT * 8) + srow * 8] = *(uint4*)&pl[sA[seg]][8];
    }
  }
  __syncthreads();  // A_lds ready; only block-wide barrier before epilogue

  // preload a kc0
#pragma unroll
  for (int i = 0; i < 4; ++i) a[0][i] = *(const bf16x8*)(ab + i * 128);

  float bestv[4][4];
  int besti[4][4];
#pragma unroll
  for (int i = 0; i < 4; ++i)
#pragma unroll
    for (int r = 0; r < 4; ++r) { bestv[i][r] = 3.4e38f; besti[i][r] = 0; }

#pragma unroll 1
  for (int ci = 0; ci < CI; ++ci) {
    const int codeBase = ci * NTC;
    const ushortT* bp0 = bci + (size_t)codeBase * 8;
    const ushortT* bp0n = bci + (size_t)(((ci + 1) & 3) * NTC) * 8;

    float h2v[4];
#pragma unroll
    for (int j = 0; j < 4; ++j) h2v[j] = h2[codeBase + wave * 64 + j * 16 + lq];

    f32x4 acc[4][4];
#pragma unroll
    for (int i = 0; i < 4; ++i)
#pragma unroll
      for (int j = 0; j < 4; ++j) acc[i][j] = (f32x4){0.f, 0.f, 0.f, 0.f};

#pragma unroll
    for (int kc = 0; kc < NKC; ++kc) {
      const int s = kc % 5;      // compile-time (full unroll)
      const int pc = kc & 1, pn = pc ^ 1;
      // a prefetch kc+1; kc=9 clamps to kc0 = next ci's a[0] (A is ci-invariant)
      const ushortT* an = (kc < NKC - 1) ? (ab + (size_t)(kc + 1) * ASTEP) : ab;
#pragma unroll
      for (int i = 0; i < 4; ++i) a[pn][i] = *(const bf16x8*)(an + i * 128);
      // MFMA cluster for kc
#pragma unroll
      for (int i = 0; i < 4; ++i)
#pragma unroll
        for (int j = 0; j < 4; ++j)
          acc[i][j] = __builtin_amdgcn_mfma_f32_16x16x32_bf16(a[pc][i], b[s][j], acc[i][j], 0, 0, 0);
      // reload slot s <- stream element kc+5 (wraps into next ci's kc0..4)
      const ushortT* bq = (kc + 5 < NKC) ? (bp0 + (size_t)(kc + 5) * KCSTEP)
                                         : (bp0n + (size_t)(kc + 5 - NKC) * KCSTEP);
#pragma unroll
      for (int j = 0; j < 4; ++j) b[s][j] = *(const bf16x8*)(bq + j * 128);
    }

    // epilogue: val = 0.5||e||^2 - f.e ; merge into per-row running best
#pragma unroll
    for (int i = 0; i < 4; ++i)
#pragma unroll
      for (int j = 0; j < 4; ++j) {
        const int idx = codeBase + wave * 64 + j * 16 + lq;
#pragma unroll
        for (int r = 0; r < 4; ++r) {
          float val = h2v[j] - acc[i][j][r];
          if (val < bestv[i][r]) { bestv[i][r] = val; besti[i][r] = idx; }  // idx ascending in (ci,j): strict < keeps lowest
        }
      }
  }

  // reduce across the 16 lanes sharing a quad (lane bits 0-3), lexicographic (val, idx)
#pragma unroll
  for (int m = 1; m < 16; m <<= 1) {
#pragma unroll
    for (int i = 0; i < 4; ++i)
#pragma unroll
      for (int r = 0; r < 4; ++r) {
        float ov = __shfl_xor(bestv[i][r], m, 64);
        int oi = __shfl_xor(besti[i][r], m, 64);
        if (ov < bestv[i][r] || (ov == bestv[i][r] && oi < besti[i][r])) {
          bestv[i][r] = ov; besti[i][r] = oi;
        }
      }
  }
  if (lq == 0) {
#pragma unroll
    for (int i = 0; i < 4; ++i)
#pragma unroll
      for (int r = 0; r < 4; ++r) {
        int row = i * 16 + quad * 4 + r;
        bvs[wave][row] = bestv[i][r];
        bis[wave][row] = besti[i][r];
      }
  }
  __syncthreads();
  if (tid < MT) {
    float bv = bvs[0][tid]; int bi = bis[0][tid];
#pragma unroll
    for (int w = 1; w < 4; ++w) {
      float ov = bvs[w][tid]; int oi = bis[w][tid];
      if (ov < bv || (ov == bv && oi < bi)) { bv = ov; bi = oi; }
    }
    widx_s[tid] = bi;
  }
  __syncthreads();
  // cooperative gather: thread handles row=tid>>2, 16 d's; emb is L2-resident (256KB)
  {
    const int row = tid >> 2, dg = (tid & 3) << 4;
    const int wi = widx_s[row];
    float4* o = (float4*)(out + (rowbase + row) * DIM + dg);
#pragma unroll
    for (int i = 0; i < 4; ++i) {
      float4 t;
      t.x = emb[(dg + 4 * i + 0) * KCODES + wi];
      t.y = emb[(dg + 4 * i + 1) * KCODES + wi];
      t.z = emb[(dg + 4 * i + 2) * KCODES + wi];
      t.w = emb[(dg + 4 * i + 3) * KCODES + wi];
      o[i] = t;
    }
  }
}

extern "C" void kernel_launch(void* const* d_in, const int* in_sizes, int n_in,
                              void* d_out, int out_size, void* d_ws, size_t ws_size,
                              hipStream_t stream) {
  const float* x = (const float*)d_in[0];
  const float* emb = (const float*)d_in[1];
  float* out = (float*)d_out;

  ushortT* Bg = (ushortT*)d_ws;               // 10*4*1024*8 ushort = 640 KB
  float* h2 = (float*)(Bg + NKC * 4 * KCODES * 8);  // 4 KB

  vq_prep<<<(NKC * 4 * KCODES * 8) / (4 * 256), 256, 0, stream>>>(emb, Bg, h2);
  vq_main<<<NROWS / MT, 256, 0, stream>>>(x, Bg, h2, emb, out);
}

// Round 3
// 286.390 us; speedup vs baseline: 1.1994x; 1.1994x over previous
//
#include <hip/hip_runtime.h>
#include <stdint.h>

typedef unsigned short ushortT;

#define NROWS 131072
#define DIM 64
#define KCODES 1024
// 5 segments (xplane,eplane) = (0,0),(0,1),(0,2),(1,0),(2,0); x1e1 dropped (~4e-6).
// R16: only 6 DISTINCT planes each side: A = {x0d0,x0d1,x1d0,x1d1,x2d0,x2d1},
// B = {e0d0,e0d1,e1d0,e1d1,e2d0,e2d1}. The 10 MFMA clusters reordered grouped
// by B-plane -> 6 B loads/ci (L2 traffic x0.6), A_lds 40->24KB, Bg 640->384KB.
#define NPL 6               // distinct planes per side
#define NCL 10              // MFMA clusters per ci (unchanged math)
#define MT 64               // rows per block (256 threads, 4 waves)
#define NTC 256             // codes per code-iter (4 waves x 64)
#define CI (KCODES / NTC)   // 4 code iters
#define KCSTEP (4 * KCODES * 8)  // ushort per B plane = 32768 (64KB)
#define ASTEP (4 * MT * 8)       // ushort per A plane = 2048 (4KB)

typedef float f32x4 __attribute__((ext_vector_type(4)));
typedef short bf16x8 __attribute__((ext_vector_type(8)));

__device__ __forceinline__ ushortT f2bf(float f) {
  union { float f; uint32_t u; } v; v.f = f;
  return (ushortT)((v.u + 0x7FFFu + ((v.u >> 16) & 1u)) >> 16);  // RNE
}
__device__ __forceinline__ float bf2f(ushortT b) {
  union { float f; uint32_t u; } v; v.u = ((uint32_t)b) << 16;
  return v.f;
}

// Output-major prep (R15-style, verified correct): flat o = p*32768 + q*8192 +
// code*8 + j; thread does 4 consecutive o (one uint2 store, coalesced).
// plane p: e-level ep = p>>1 (bf16 split plane), d-half = p&1.
// ep block-uniform (block spans 1024 flat elems < 32768 plane size, aligned).
// h2[code] = 0.5*||e||^2 fp32 by blocks 0..3. Same f2bf math as R13.
__global__ __launch_bounds__(256) void vq_prep(const float* __restrict__ emb,
                                               ushortT* __restrict__ Bg,
                                               float* __restrict__ h2) {
  const int o4 = (blockIdx.x * 256 + threadIdx.x) * 4;
  const int j0 = o4 & 7;                  // 0 or 4
  const int code = (o4 >> 3) & (KCODES - 1);
  const int q = (o4 >> 13) & 3;
  const int p = o4 >> 15;                 // 0..5 (block-uniform)
  const int ep = p >> 1;
  const int d0 = (p & 1) * 32 + q * 8 + j0;

  ushortT outv[4];
#pragma unroll
  for (int t = 0; t < 4; ++t) {
    float e = emb[(d0 + t) * KCODES + code];
    ushortT p0 = f2bf(e);
    ushortT pv = p0;
    if (ep == 1) {
      float r1 = e - bf2f(p0);            // exact (Sterbenz)
      pv = f2bf(r1);
    } else if (ep == 2) {
      float r1 = e - bf2f(p0);
      ushortT p1 = f2bf(r1);
      float r2 = r1 - bf2f(p1);           // exact
      pv = f2bf(r2);
    }
    outv[t] = pv;
  }
  *(uint2*)(&Bg[o4]) = *(const uint2*)(&outv[0]);

  if (blockIdx.x < 4) {
    const int c2 = blockIdx.x * 256 + threadIdx.x;
    float s = 0.f;
#pragma unroll
    for (int d = 0; d < DIM; ++d) {
      float e = emb[d * KCODES + c2];
      s = fmaf(e, e, s);
    }
    h2[c2] = 0.5f * s;
  }
}

// R16: R13 structure (verified 121us, MfmaUtil 30% == L2-BW-bound model) with
// plane-dedup'd loads. Cluster order (orig kc): {0,6,8, 1,7,9, 2, 3, 4, 5} —
// grouped by B plane so each of the 6 distinct B planes is loaded ONCE per ci.
// 3-slot B ring: s0<-e0d0, s1<-e0d1, s2<-e1d0 preloaded; reloads after
// clusters 2(s0<-e1d1), 5(s1<-e2d0), 6(s2<-e2d1), 7(s0<-next e0d0),
// 8(s1<-next e0d1), 9(s2<-next e1d0). Slot phase is ci-invariant -> pipeline
// never drains across ci; every reload->use distance >= 2 clusters (~200cy).
// Register delta vs R13: +16 (b ring 48 vs 32) -> ~152 unified, under the
// 170 limit for launch_bounds(256,3). Accum order change: fp32 reorder noise
// ~1e-6 << tolerated ~6e-5 perturbation of the verified 5-seg config.
__global__ __launch_bounds__(256, 3) void vq_main(const float* __restrict__ x,
                                                  const ushortT* __restrict__ Bg,
                                                  const float* __restrict__ h2,
                                                  const float* __restrict__ emb,
                                                  float* __restrict__ out) {
  __shared__ ushortT A_lds[NPL * ASTEP];  // 24 KB  [plane][quad][row][8]
  __shared__ float bvs[4][MT];
  __shared__ int bis[4][MT];
  __shared__ int widx_s[MT];

  const int tid = threadIdx.x;
  const int wave = tid >> 6, lane = tid & 63, quad = lane >> 4, lq = lane & 15;
  const size_t rowbase = (size_t)blockIdx.x * MT;

  const ushortT* bci = Bg + ((size_t)(quad * KCODES + wave * 64 + lq)) * 8;
  const ushortT* ab = &A_lds[quad * (MT * 8) + lq * 8];

  // ---- stage A: x rows -> bf16 planes, frag-major, dedup'd (6 planes) ----
  {
    const int row = tid >> 2, dg = (tid & 3) << 4;
    const float4* xr = (const float4*)(x + (rowbase + row) * DIM + dg);
    float v[16];
#pragma unroll
    for (int i = 0; i < 4; ++i) {
      float4 t = xr[i];
      v[4 * i] = t.x; v[4 * i + 1] = t.y; v[4 * i + 2] = t.z; v[4 * i + 3] = t.w;
    }
    ushortT pl[3][16];
#pragma unroll
    for (int i = 0; i < 16; ++i) {
      ushortT a0 = f2bf(v[i]); float r1 = v[i] - bf2f(a0);
      ushortT a1 = f2bf(r1);   float r2 = r1 - bf2f(a1);
      pl[0][i] = a0; pl[1][i] = a1; pl[2][i] = f2bf(r2);
    }
    const int q0 = (dg & 31) >> 3;         // 0 or 2
    const int dh = dg >> 5;                // d-half
#pragma unroll
    for (int xp = 0; xp < 3; ++xp) {
      int pa = xp * 2 + dh;
      *(uint4*)&A_lds[pa * ASTEP + q0 * (MT * 8) + row * 8]       = *(uint4*)&pl[xp][0];
      *(uint4*)&A_lds[pa * ASTEP + (q0 + 1) * (MT * 8) + row * 8] = *(uint4*)&pl[xp][8];
    }
  }
  __syncthreads();  // A_lds ready; only block-wide barrier before epilogue

  bf16x8 a[2][4], b[3][4];
  // preload B ring for ci0: s0<-plane0 (e0d0), s1<-plane1 (e0d1), s2<-plane2 (e1d0)
#pragma unroll
  for (int s = 0; s < 3; ++s)
#pragma unroll
    for (int j = 0; j < 4; ++j)
      b[s][j] = *(const bf16x8*)(bci + (size_t)s * KCSTEP + j * 128);
  // preload a[0] <- plane0 (x0d0)
#pragma unroll
  for (int i = 0; i < 4; ++i) a[0][i] = *(const bf16x8*)(ab + i * 128);

  float bestv[4][4];
  int besti[4][4];
#pragma unroll
  for (int i = 0; i < 4; ++i)
#pragma unroll
    for (int r = 0; r < 4; ++r) { bestv[i][r] = 3.4e38f; besti[i][r] = 0; }

  // cluster schedule (compile-time): a-plane, b-slot, reload (slot,plane,next-ci?)
  const int APL[NCL] = {0, 2, 4, 1, 3, 5, 0, 1, 0, 1};
  const int BSL[NCL] = {0, 0, 0, 1, 1, 1, 2, 0, 1, 2};
  const int RLS[NCL] = {-1, -1, 0, -1, -1, 1, 2, 0, 1, 2};
  const int RLP[NCL] = {0, 0, 3, 0, 0, 4, 5, 0, 1, 2};
  const int RNX[NCL] = {0, 0, 0, 0, 0, 0, 0, 1, 1, 1};

#pragma unroll 1
  for (int ci = 0; ci < CI; ++ci) {
    const int codeBase = ci * NTC;
    const ushortT* bcur = bci + (size_t)codeBase * 8;
    const ushortT* bnxt = bci + (size_t)(((ci + 1) & 3) * NTC) * 8;

    f32x4 acc[4][4];
#pragma unroll
    for (int i = 0; i < 4; ++i)
#pragma unroll
      for (int j = 0; j < 4; ++j) acc[i][j] = (f32x4){0.f, 0.f, 0.f, 0.f};

#pragma unroll
    for (int c = 0; c < NCL; ++c) {
      const int pc = c & 1, pn = pc ^ 1;
      // prefetch next cluster's a-plane (c=9: next ci's cluster0 plane = 0)
      const int apn = (c < NCL - 1) ? APL[c + 1] : APL[0];
#pragma unroll
      for (int i = 0; i < 4; ++i)
        a[pn][i] = *(const bf16x8*)(ab + (size_t)apn * ASTEP + i * 128);
      // MFMA cluster
      const int s = BSL[c];
#pragma unroll
      for (int i = 0; i < 4; ++i)
#pragma unroll
        for (int j = 0; j < 4; ++j)
          acc[i][j] = __builtin_amdgcn_mfma_f32_16x16x32_bf16(a[pc][i], b[s][j], acc[i][j], 0, 0, 0);
      // ring reload (after last use of this slot's current contents)
      if (RLS[c] >= 0) {
        const ushortT* bq = (RNX[c] ? bnxt : bcur) + (size_t)RLP[c] * KCSTEP;
#pragma unroll
        for (int j = 0; j < 4; ++j)
          b[RLS[c]][j] = *(const bf16x8*)(bq + j * 128);
      }
    }

    // epilogue: val = 0.5||e||^2 - f.e ; merge into per-row running best
    float h2v[4];
#pragma unroll
    for (int j = 0; j < 4; ++j) h2v[j] = h2[codeBase + wave * 64 + j * 16 + lq];
#pragma unroll
    for (int i = 0; i < 4; ++i)
#pragma unroll
      for (int j = 0; j < 4; ++j) {
        const int idx = codeBase + wave * 64 + j * 16 + lq;
#pragma unroll
        for (int r = 0; r < 4; ++r) {
          float val = h2v[j] - acc[i][j][r];
          if (val < bestv[i][r]) { bestv[i][r] = val; besti[i][r] = idx; }  // idx ascending in (ci,j): strict < keeps lowest
        }
      }
  }

  // reduce across the 16 lanes sharing a quad (lane bits 0-3), lexicographic (val, idx)
#pragma unroll
  for (int m = 1; m < 16; m <<= 1) {
#pragma unroll
    for (int i = 0; i < 4; ++i)
#pragma unroll
      for (int r = 0; r < 4; ++r) {
        float ov = __shfl_xor(bestv[i][r], m, 64);
        int oi = __shfl_xor(besti[i][r], m, 64);
        if (ov < bestv[i][r] || (ov == bestv[i][r] && oi < besti[i][r])) {
          bestv[i][r] = ov; besti[i][r] = oi;
        }
      }
  }
  if (lq == 0) {
#pragma unroll
    for (int i = 0; i < 4; ++i)
#pragma unroll
      for (int r = 0; r < 4; ++r) {
        int row = i * 16 + quad * 4 + r;
        bvs[wave][row] = bestv[i][r];
        bis[wave][row] = besti[i][r];
      }
  }
  __syncthreads();
  if (tid < MT) {
    float bv = bvs[0][tid]; int bi = bis[0][tid];
#pragma unroll
    for (int w = 1; w < 4; ++w) {
      float ov = bvs[w][tid]; int oi = bis[w][tid];
      if (ov < bv || (ov == bv && oi < bi)) { bv = ov; bi = oi; }
    }
    widx_s[tid] = bi;
  }
  __syncthreads();
  // cooperative gather: thread handles row=tid>>2, 16 d's; emb is L2-resident (256KB)
  {
    const int row = tid >> 2, dg = (tid & 3) << 4;
    const int wi = widx_s[row];
    float4* o = (float4*)(out + (rowbase + row) * DIM + dg);
#pragma unroll
    for (int i = 0; i < 4; ++i) {
      float4 t;
      t.x = emb[(dg + 4 * i + 0) * KCODES + wi];
      t.y = emb[(dg + 4 * i + 1) * KCODES + wi];
      t.z = emb[(dg + 4 * i + 2) * KCODES + wi];
      t.w = emb[(dg + 4 * i + 3) * KCODES + wi];
      o[i] = t;
    }
  }
}

extern "C" void kernel_launch(void* const* d_in, const int* in_sizes, int n_in,
                              void* d_out, int out_size, void* d_ws, size_t ws_size,
                              hipStream_t stream) {
  const float* x = (const float*)d_in[0];
  const float* emb = (const float*)d_in[1];
  float* out = (float*)d_out;

  ushortT* Bg = (ushortT*)d_ws;               // 6*32768 ushort = 384 KB
  float* h2 = (float*)(Bg + NPL * (size_t)KCSTEP);  // 4 KB

  vq_prep<<<(NPL * KCSTEP) / (4 * 256), 256, 0, stream>>>(emb, Bg, h2);
  vq_main<<<NROWS / MT, 256, 0, stream>>>(x, Bg, h2, emb, out);
}